// Round 6
// baseline (697.950 us; speedup 1.0000x reference)
//
#include <hip/hip_runtime.h>
#include <hip/hip_bf16.h>

typedef float    f4v    __attribute__((ext_vector_type(4)));
typedef short    short8 __attribute__((ext_vector_type(8)));
typedef unsigned u2v    __attribute__((ext_vector_type(2)));

constexpr int Bn = 4096, TR = 16;

// ---- split-bf16 helpers ----------------------------------------------------
__device__ inline unsigned cvt2(float x, float y) {
  union { __hip_bfloat162 h; unsigned u; } c;
  c.h = __float22bfloat162_rn(float2{x, y});
  return c.u;   // low16 = bf16(x), high16 = bf16(y)
}
__device__ inline void split_pair(float x, float y, unsigned& hp, unsigned& lp) {
  hp = cvt2(x, y);
  float hx = __uint_as_float(hp << 16);
  float hy = __uint_as_float(hp & 0xffff0000u);
  lp = cvt2(x - hx, y - hy);
}
union S8U { unsigned u[4]; short8 s; };
__device__ inline void split8(const float v[8], short8& hi, short8& lo) {
  S8U h, l;
  #pragma unroll
  for (int d = 0; d < 4; ++d) split_pair(v[2 * d], v[2 * d + 1], h.u[d], l.u[d]);
  hi = h.s; lo = l.s;
}
__device__ inline void split8p(const float* p, short8& hi, short8& lo) {
  f4v a = *(const f4v*)p, b = *(const f4v*)(p + 4);
  float v[8] = {a[0], a[1], a[2], a[3], b[0], b[1], b[2], b[3]};
  split8(v, hi, lo);
}
__device__ inline f4v mfma16(short8 a, short8 b, f4v c) {
  return __builtin_amdgcn_mfma_f32_16x16x32_bf16(a, b, c, 0, 0, 0);
}
__device__ __attribute__((always_inline)) inline f4v gdot8(
    const short8 (&ah)[8], const short8 (&al)[8],
    const short8 (&bh)[8], const short8 (&bl)[8]) {
  f4v c = {0.f, 0.f, 0.f, 0.f};
  #pragma unroll
  for (int s = 0; s < 8; ++s) {
    c = mfma16(ah[s], bh[s], c);
    c = mfma16(al[s], bh[s], c);
    c = mfma16(ah[s], bl[s], c);
  }
  return c;
}

// pack 4 fp32 -> bf16 hi/lo fragment words, write hi at dst[0..1], lo at dst[256..257]
__device__ inline void pack_write(unsigned* dst, float z0, float z1, float z2, float z3) {
  unsigned a0, b0, a1, b1;
  split_pair(z0, z1, a0, b0);
  split_pair(z2, z3, a1, b1);
  u2v hv; hv[0] = a0; hv[1] = a1;
  u2v lv; lv[0] = b0; lv[1] = b1;
  *(u2v*)&dst[0]   = hv;
  *(u2v*)&dst[256] = lv;
}

// ---------------------------------------------------------------------------
// k_prep: KAT[n][m] = (inv(A A^T + 1e-6 I) @ A)^T -> ws. 1 block, 256 thr.
// ---------------------------------------------------------------------------
__global__ __launch_bounds__(256) void k_prep(const float* __restrict__ A,
                                              float* __restrict__ KAT) {
  __shared__ __align__(16) float As[32 * 256];
  __shared__ float Gm[32 * 68];
  __shared__ float GinvL[32 * 32];

  const int t = threadIdx.x;
  const int lane = t & 63, wv = t >> 6, quad = lane >> 4, l15 = lane & 15;
  const int T = wv & 1, kh = wv >> 1;

  for (int i = t; i < 2048; i += 256)
    ((f4v*)As)[i] = ((const f4v*)A)[i];
  __syncthreads();

  // G = A A^T (+ eps I): wave = 16x16 tile
  {
    short8 afh[2][8], afl[2][8];
    #pragma unroll
    for (int tt = 0; tt < 2; ++tt)
      #pragma unroll
      for (int s = 0; s < 8; ++s)
        split8p(As + (l15 + 16 * tt) * 256 + 32 * s + 8 * quad,
                afh[tt][s], afl[tt][s]);
    f4v cg;
    if      (wv == 0) cg = gdot8(afh[0], afl[0], afh[0], afl[0]);
    else if (wv == 1) cg = gdot8(afh[1], afl[1], afh[0], afl[0]);
    else if (wv == 2) cg = gdot8(afh[0], afl[0], afh[1], afl[1]);
    else              cg = gdot8(afh[1], afl[1], afh[1], afl[1]);
    #pragma unroll
    for (int r = 0; r < 4; ++r) {
      int gi = 16 * T + 4 * quad + r, gj = 16 * kh + l15;
      Gm[gi * 68 + gj]      = cg[r] + (gi == gj ? 1e-6f : 0.f);
      Gm[gi * 68 + 32 + gj] = (gi == gj) ? 1.f : 0.f;
    }
  }
  __syncthreads();

  // Gauss-Jordan on wave 0: lane = augmented column
  if (wv == 0) {
    float gcol[32];
    #pragma unroll
    for (int i = 0; i < 32; ++i) gcol[i] = Gm[i * 68 + lane];
    #pragma unroll
    for (int k = 0; k < 32; ++k) {
      float ckk  = __shfl(gcol[k], k);
      float ipiv = 1.f / ckk;
      float pivj = gcol[k] * ipiv;
      gcol[k] = pivj;
      #pragma unroll
      for (int i = 0; i < 32; ++i) {
        if (i == k) continue;
        float cki = __shfl(gcol[i], k);
        gcol[i] = fmaf(-cki, pivj, gcol[i]);
      }
    }
    if (lane >= 32) {
      #pragma unroll
      for (int i = 0; i < 32; ++i) GinvL[i * 32 + (lane - 32)] = gcol[i];
    }
  }
  __syncthreads();

  // KAT[n=t][m] = sum_p As[p][n] * Ginv[p][m]
  {
    float res[32];
    #pragma unroll
    for (int m = 0; m < 32; ++m) res[m] = 0.f;
    for (int p = 0; p < 32; ++p) {
      float av = As[p * 256 + t];
      #pragma unroll
      for (int m4 = 0; m4 < 8; ++m4) {
        f4v g = *(const f4v*)&GinvL[p * 32 + 4 * m4];
        res[4 * m4 + 0] = fmaf(av, g[0], res[4 * m4 + 0]);
        res[4 * m4 + 1] = fmaf(av, g[1], res[4 * m4 + 1]);
        res[4 * m4 + 2] = fmaf(av, g[2], res[4 * m4 + 2]);
        res[4 * m4 + 3] = fmaf(av, g[3], res[4 * m4 + 3]);
      }
    }
    #pragma unroll
    for (int m4 = 0; m4 < 8; ++m4) {
      f4v v = {res[4 * m4], res[4 * m4 + 1], res[4 * m4 + 2], res[4 * m4 + 3]};
      *(f4v*)&KAT[t * 32 + 4 * m4] = v;
    }
  }
}

// ---------------------------------------------------------------------------
// k_prep2: QT[n][k] = (n==k) - sum_m A[m][k]*KAT[n][m]  (= (I-P)^T rows),
// pre-split into bf16 hi/lo words. 64 blocks x 256 thr; wave = one n-row.
// ---------------------------------------------------------------------------
__global__ __launch_bounds__(256) void k_prep2(const float* __restrict__ A,
                                               const float* __restrict__ KAT,
                                               unsigned* __restrict__ QTH,
                                               unsigned* __restrict__ QTL) {
  const int t = threadIdx.x, lane = t & 63, wv = t >> 6;
  const int n = blockIdx.x * 4 + wv;
  const int k0 = lane * 4;
  const float* kr = KAT + n * 32;
  f4v p = {0.f, 0.f, 0.f, 0.f};
  #pragma unroll
  for (int m = 0; m < 32; ++m) {
    float km = kr[m];
    f4v av = *(const f4v*)&A[m * 256 + k0];
    p[0] = fmaf(km, av[0], p[0]);
    p[1] = fmaf(km, av[1], p[1]);
    p[2] = fmaf(km, av[2], p[2]);
    p[3] = fmaf(km, av[3], p[3]);
  }
  float q0 = ((k0 + 0) == n ? 1.f : 0.f) - p[0];
  float q1 = ((k0 + 1) == n ? 1.f : 0.f) - p[1];
  float q2 = ((k0 + 2) == n ? 1.f : 0.f) - p[2];
  float q3 = ((k0 + 3) == n ? 1.f : 0.f) - p[3];
  unsigned a0, b0, a1, b1;
  split_pair(q0, q1, a0, b0);
  split_pair(q2, q3, a1, b1);
  u2v hv; hv[0] = a0; hv[1] = a1;
  u2v lv; lv[0] = b0; lv[1] = b1;
  *(u2v*)&QTH[n * 128 + lane * 2] = hv;
  *(u2v*)&QTL[n * 128 + lane * 2] = lv;
}

// ---------------------------------------------------------------------------
// k_main: 1024 threads (16 waves), TR=16 rows/block, grid 256 = 1 block/CU.
// Fused iteration u = z@Q + c, K-SPLIT across wave pairs:
//   16 waves = 8 n-pair-groups x 2 k-halves. Wave (g,h) holds Q hi/lo frags
//   for BOTH tiles {2g, 2g+1} over k-half h only -> 16 short8 = 64 VGPR.
//   Total demand ~122 <= the 128-VGPR cap this compiler enforces for large
//   blocks (R1-R5 evidence: 512-thr blocks pin at 128; remat/spill otherwise).
//   Per iter: wave reads 8 KB of z (its k-half), 24 MFMA, posts partner-tile
//   partial to LDS, barrier, sums own partial + partner partial + c.
//   Two barriers/iter; zfrag double-buffered; z state fp32 in registers.
//   LDS/iter/CU ~ 176 KB (vs 256 KB for 16-wave full-K broadcast).
// ---------------------------------------------------------------------------
__global__ __launch_bounds__(1024, 4)
void k_main(
    const float* __restrict__ x,  const float* __restrict__ bmat,
    const float* __restrict__ W1, const float* __restrict__ b1,
    const float* __restrict__ W2, const float* __restrict__ b2,
    const float* __restrict__ W3, const float* __restrict__ b3,
    const float* __restrict__ KAT,
    const short* __restrict__ QTHs, const short* __restrict__ QTLs,
    const int* __restrict__ n_iter_p, float* __restrict__ out) {

  __shared__ __align__(16) float    ubuf[8768];    // MLP scratch; later pbuf
  // zfrag: only [0..8191] used (double buffer at 0 / 4096). Padded to keep
  // LDS > 80 KB -> exactly 1 block/CU.
  __shared__ __align__(16) unsigned zfrag[12288];

  const int t = threadIdx.x;
  const int lane = t & 63, wv = t >> 6, quad = lane >> 4, l15 = lane & 15;
  const int row0 = blockIdx.x * TR;

  float* xs = ubuf;            // [16][132]
  float* h1 = ubuf + 2112;     // [16][208]
  float* h2 = ubuf + 5440;     // [16][208]
  float* ys = ubuf;            // [16][260] (xs+h1 dead by then)

  if (t < 512) {
    int r = t >> 5, c4 = t & 31;
    *(f4v*)&xs[r * 132 + 4 * c4] = *(const f4v*)&x[(size_t)(row0 + r) * 128 + 4 * c4];
  }
  __syncthreads();

  // ---- MLP: 1 row per wave (16 waves = 16 rows) ----
  {
    const int rr = wv, oc = lane;
    const bool g3 = (oc < 8);    // HID=200: col oc+192 valid iff oc<8
    float acc[4];

    // L1: 128 -> 200, relu
    #pragma unroll
    for (int oi = 0; oi < 4; ++oi) acc[oi] = 0.f;
    for (int k4 = 0; k4 < 32; ++k4) {
      f4v xv = *(const f4v*)&xs[rr * 132 + 4 * k4];
      #pragma unroll
      for (int kk = 0; kk < 4; ++kk) {
        const float* wr = W1 + (4 * k4 + kk) * 200 + oc;
        float w0 = wr[0], w1c = wr[64], w2c = wr[128];
        float w3c = g3 ? wr[192] : 0.f;
        acc[0] = fmaf(xv[kk], w0, acc[0]);
        acc[1] = fmaf(xv[kk], w1c, acc[1]);
        acc[2] = fmaf(xv[kk], w2c, acc[2]);
        acc[3] = fmaf(xv[kk], w3c, acc[3]);
      }
    }
    #pragma unroll
    for (int oi = 0; oi < 4; ++oi) {
      if (oi == 3 && !g3) continue;
      h1[rr * 208 + oc + 64 * oi] = fmaxf(acc[oi] + b1[oc + 64 * oi], 0.f);
    }
    __syncthreads();

    // L2: 200 -> 200, relu
    #pragma unroll
    for (int oi = 0; oi < 4; ++oi) acc[oi] = 0.f;
    for (int k4 = 0; k4 < 50; ++k4) {
      f4v xv = *(const f4v*)&h1[rr * 208 + 4 * k4];
      #pragma unroll
      for (int kk = 0; kk < 4; ++kk) {
        const float* wr = W2 + (4 * k4 + kk) * 200 + oc;
        float w0 = wr[0], w1c = wr[64], w2c = wr[128];
        float w3c = g3 ? wr[192] : 0.f;
        acc[0] = fmaf(xv[kk], w0, acc[0]);
        acc[1] = fmaf(xv[kk], w1c, acc[1]);
        acc[2] = fmaf(xv[kk], w2c, acc[2]);
        acc[3] = fmaf(xv[kk], w3c, acc[3]);
      }
    }
    __syncthreads();   // h1 reads done before h2 write (h2 disjoint, but cheap)
    #pragma unroll
    for (int oi = 0; oi < 4; ++oi) {
      if (oi == 3 && !g3) continue;
      h2[rr * 208 + oc + 64 * oi] = fmaxf(acc[oi] + b2[oc + 64 * oi], 0.f);
    }
    __syncthreads();

    // L3: 200 -> 256 (no relu) -> ys
    #pragma unroll
    for (int oi = 0; oi < 4; ++oi) acc[oi] = 0.f;
    for (int k4 = 0; k4 < 50; ++k4) {
      f4v xv = *(const f4v*)&h2[rr * 208 + 4 * k4];
      #pragma unroll
      for (int kk = 0; kk < 4; ++kk) {
        const float* wr = W3 + (4 * k4 + kk) * 256 + oc;
        float w0 = wr[0], w1c = wr[64], w2c = wr[128], w3c = wr[192];
        acc[0] = fmaf(xv[kk], w0, acc[0]);
        acc[1] = fmaf(xv[kk], w1c, acc[1]);
        acc[2] = fmaf(xv[kk], w2c, acc[2]);
        acc[3] = fmaf(xv[kk], w3c, acc[3]);
      }
    }
    __syncthreads();   // all reads of h2/xs done before ys overlays ubuf
    #pragma unroll
    for (int oi = 0; oi < 4; ++oi)
      ys[rr * 260 + oc + 64 * oi] = acc[oi] + b3[oc + 64 * oi];
  }
  __syncthreads();

  // ---- wave role: n-pair-group ng (0..7), k-half kh (0..1) ----
  const int ng = wv & 7, kh = wv >> 3;
  const int Uown = 2 * ng + kh;       // tile this wave owns (z state, update)
  const int Upar = 2 * ng + 1 - kh;   // partner's tile (we post its partial)

  // ---- c = b @ KAT^T for own tile (bv regs die before Q loads) ----
  f4v crv;
  {
    float bv[32];
    #pragma unroll
    for (int m4 = 0; m4 < 8; ++m4)
      *(f4v*)&bv[4 * m4] = *(const f4v*)&bmat[(size_t)(row0 + l15) * 32 + 4 * m4];
    #pragma unroll
    for (int r = 0; r < 4; ++r) {
      const float* kp = KAT + (size_t)(16 * Uown + 4 * quad + r) * 32;
      float s = 0.f;
      #pragma unroll
      for (int m4 = 0; m4 < 8; ++m4) {
        f4v kv = *(const f4v*)&kp[4 * m4];
        s = fmaf(bv[4 * m4 + 0], kv[0], s);
        s = fmaf(bv[4 * m4 + 1], kv[1], s);
        s = fmaf(bv[4 * m4 + 2], kv[2], s);
        s = fmaf(bv[4 * m4 + 3], kv[3], s);
      }
      crv[r] = s;
    }
  }
  asm volatile("" : "+v"(crv));

  // ---- Q^T fragments: both tiles of the pair, k-half kh only ----
  // 16 short8 = 64 VGPR. Opacity pins forbid in-loop remat (R2 lesson).
  short8 qhO[4], qlO[4], qhP[4], qlP[4];
  #pragma unroll
  for (int so = 0; so < 4; ++so) {
    const int s = 4 * kh + so;
    const int nO = 16 * Uown + l15, nP = 16 * Upar + l15;
    qhO[so] = *(const short8*)&QTHs[nO * 256 + 32 * s + 8 * quad];
    qlO[so] = *(const short8*)&QTLs[nO * 256 + 32 * s + 8 * quad];
    qhP[so] = *(const short8*)&QTHs[nP * 256 + 32 * s + 8 * quad];
    qlP[so] = *(const short8*)&QTLs[nP * 256 + 32 * s + 8 * quad];
  }
  #pragma unroll
  for (int so = 0; so < 4; ++so)
    asm volatile("" : "+v"(qhO[so]), "+v"(qlO[so]), "+v"(qhP[so]), "+v"(qlP[so]));

  // ---- z init for own tile; publish buffer 0 ----
  const int qp = 2 * (Uown & 1) + (quad >> 1);
  const int zoff = ((Uown >> 1) * 2) * 256 + qp * 64 + l15 * 4 + 2 * (quad & 1);
  float zr[4];
  {
    f4v yv = *(const f4v*)&ys[l15 * 260 + 16 * Uown + 4 * quad];
    #pragma unroll
    for (int r = 0; r < 4; ++r) zr[r] = yv[r];
    pack_write(&zfrag[zoff], zr[0], zr[1], zr[2], zr[3]);
  }
  __syncthreads();

  const int niter = n_iter_p[0];
  const int zrd = lane * 4;
  float* pbuf = ubuf;                       // 16 KB partial exchange (ubuf dead)
  const int pwr = (Upar * 64 + lane) * 4;   // write partner-tile partial
  const int prd = (Uown * 64 + lane) * 4;   // read own-tile partial from partner

  for (int it = 0; it <= niter; ++it) {
    const unsigned* zb = zfrag + ((it & 1) << 12);         // read buffer
    unsigned*       zw = zfrag + (((it & 1) ^ 1) << 12);   // write buffer

    // partial u over k-half kh for tiles Uown (O) and Upar (P): 6 chains
    f4v uAo = {0.f,0.f,0.f,0.f}, uBo = {0.f,0.f,0.f,0.f}, uCo = {0.f,0.f,0.f,0.f};
    f4v uAp = {0.f,0.f,0.f,0.f}, uBp = {0.f,0.f,0.f,0.f}, uCp = {0.f,0.f,0.f,0.f};
    #pragma unroll
    for (int so = 0; so < 4; ++so) {
      const int s = 4 * kh + so;
      short8 zh = *(const short8*)&zb[(2 * s + 0) * 256 + zrd];
      short8 zl = *(const short8*)&zb[(2 * s + 1) * 256 + zrd];
      uAo = mfma16(qhO[so], zh, uAo);
      uAp = mfma16(qhP[so], zh, uAp);
      uBo = mfma16(qlO[so], zh, uBo);
      uBp = mfma16(qlP[so], zh, uBp);
      uCo = mfma16(qhO[so], zl, uCo);
      uCp = mfma16(qhP[so], zl, uCp);
    }
    f4v pO = (uAo + uBo) + uCo;
    f4v pP = (uAp + uBp) + uCp;
    *(f4v*)&pbuf[pwr] = pP;
    __syncthreads();                         // partials visible
    f4v uf = (pO + *(const f4v*)&pbuf[prd]) + crv;

    if (it < niter) {
      float zn[4];
      #pragma unroll
      for (int r = 0; r < 4; ++r) {
        float uv = uf[r], z = zr[r];
        float vv = fminf(fmaxf(fmaf(2.f, uv, -z), 0.f), 1.f);  // clip(2u - z)
        zn[r] = fmaf(1.7f, vv - uv, z);                        // z += 1.7*(v-u)
        zr[r] = zn[r];
      }
      pack_write(&zw[zoff], zn[0], zn[1], zn[2], zn[3]);
      __syncthreads();                       // zw (and pbuf reuse) safe
    } else {
      *(f4v*)&out[(size_t)(row0 + l15) * 256 + 16 * Uown + 4 * quad] = uf;
    }
  }
}

// ---------------------------------------------------------------------------
extern "C" void kernel_launch(void* const* d_in, const int* in_sizes, int n_in,
                              void* d_out, int out_size, void* d_ws, size_t ws_size,
                              hipStream_t stream) {
  const float* x    = (const float*)d_in[0];
  const float* bmat = (const float*)d_in[1];
  const float* W1   = (const float*)d_in[2];
  const float* b1   = (const float*)d_in[3];
  const float* W2   = (const float*)d_in[4];
  const float* b2   = (const float*)d_in[5];
  const float* W3   = (const float*)d_in[6];
  const float* b3   = (const float*)d_in[7];
  const float* A    = (const float*)d_in[8];
  const int*  n_it  = (const int*)d_in[10];

  float*    KAT = (float*)d_ws;                       // 256*32 f32   = 32 KB
  unsigned* QTH = (unsigned*)((char*)d_ws + 32768);   // 256*256 bf16 = 128 KB
  unsigned* QTL = QTH + 256 * 128;                    // 256*256 bf16 = 128 KB
  float* out = (float*)d_out;

  hipLaunchKernelGGL(k_prep,  dim3(1),       dim3(256), 0, stream, A, KAT);
  hipLaunchKernelGGL(k_prep2, dim3(64),      dim3(256), 0, stream, A, KAT, QTH, QTL);
  hipLaunchKernelGGL(k_main,  dim3(Bn / TR), dim3(1024), 0, stream,
                     x, bmat, W1, b1, W2, b2, W3, b3, KAT,
                     (const short*)QTH, (const short*)QTL, n_it, out);
}

// Round 7
// 227.112 us; speedup vs baseline: 3.0732x; 3.0732x over previous
//
#include <hip/hip_runtime.h>
#include <hip/hip_bf16.h>

typedef float    f4v    __attribute__((ext_vector_type(4)));
typedef short    short8 __attribute__((ext_vector_type(8)));
typedef unsigned u2v    __attribute__((ext_vector_type(2)));

constexpr int Bn = 4096, TR = 16;

// ---- split-bf16 helpers ----------------------------------------------------
__device__ inline unsigned cvt2(float x, float y) {
  union { __hip_bfloat162 h; unsigned u; } c;
  c.h = __float22bfloat162_rn(float2{x, y});
  return c.u;   // low16 = bf16(x), high16 = bf16(y)
}
__device__ inline void split_pair(float x, float y, unsigned& hp, unsigned& lp) {
  hp = cvt2(x, y);
  float hx = __uint_as_float(hp << 16);
  float hy = __uint_as_float(hp & 0xffff0000u);
  lp = cvt2(x - hx, y - hy);
}
union S8U { unsigned u[4]; short8 s; };
__device__ inline void split8(const float v[8], short8& hi, short8& lo) {
  S8U h, l;
  #pragma unroll
  for (int d = 0; d < 4; ++d) split_pair(v[2 * d], v[2 * d + 1], h.u[d], l.u[d]);
  hi = h.s; lo = l.s;
}
__device__ inline void split8p(const float* p, short8& hi, short8& lo) {
  f4v a = *(const f4v*)p, b = *(const f4v*)(p + 4);
  float v[8] = {a[0], a[1], a[2], a[3], b[0], b[1], b[2], b[3]};
  split8(v, hi, lo);
}
__device__ inline f4v mfma16(short8 a, short8 b, f4v c) {
  return __builtin_amdgcn_mfma_f32_16x16x32_bf16(a, b, c, 0, 0, 0);
}
__device__ __attribute__((always_inline)) inline f4v gdot8(
    const short8 (&ah)[8], const short8 (&al)[8],
    const short8 (&bh)[8], const short8 (&bl)[8]) {
  f4v c = {0.f, 0.f, 0.f, 0.f};
  #pragma unroll
  for (int s = 0; s < 8; ++s) {
    c = mfma16(ah[s], bh[s], c);
    c = mfma16(al[s], bh[s], c);
    c = mfma16(ah[s], bl[s], c);
  }
  return c;
}

// pack 4 fp32 -> bf16 hi/lo fragment words, write hi at dst[0..1], lo at dst[256..257]
__device__ inline void pack_write(unsigned* dst, float z0, float z1, float z2, float z3) {
  unsigned a0, b0, a1, b1;
  split_pair(z0, z1, a0, b0);
  split_pair(z2, z3, a1, b1);
  u2v hv; hv[0] = a0; hv[1] = a1;
  u2v lv; lv[0] = b0; lv[1] = b1;
  *(u2v*)&dst[0]   = hv;
  *(u2v*)&dst[256] = lv;
}

// ---------------------------------------------------------------------------
// k_prep: KAT[n][m] = (inv(A A^T + 1e-6 I) @ A)^T -> ws. 1 block, 256 thr.
// ---------------------------------------------------------------------------
__global__ __launch_bounds__(256) void k_prep(const float* __restrict__ A,
                                              float* __restrict__ KAT) {
  __shared__ __align__(16) float As[32 * 256];
  __shared__ float Gm[32 * 68];
  __shared__ float GinvL[32 * 32];

  const int t = threadIdx.x;
  const int lane = t & 63, wv = t >> 6, quad = lane >> 4, l15 = lane & 15;
  const int T = wv & 1, kh = wv >> 1;

  for (int i = t; i < 2048; i += 256)
    ((f4v*)As)[i] = ((const f4v*)A)[i];
  __syncthreads();

  // G = A A^T (+ eps I): wave = 16x16 tile
  {
    short8 afh[2][8], afl[2][8];
    #pragma unroll
    for (int tt = 0; tt < 2; ++tt)
      #pragma unroll
      for (int s = 0; s < 8; ++s)
        split8p(As + (l15 + 16 * tt) * 256 + 32 * s + 8 * quad,
                afh[tt][s], afl[tt][s]);
    f4v cg;
    if      (wv == 0) cg = gdot8(afh[0], afl[0], afh[0], afl[0]);
    else if (wv == 1) cg = gdot8(afh[1], afl[1], afh[0], afl[0]);
    else if (wv == 2) cg = gdot8(afh[0], afl[0], afh[1], afl[1]);
    else              cg = gdot8(afh[1], afl[1], afh[1], afl[1]);
    #pragma unroll
    for (int r = 0; r < 4; ++r) {
      int gi = 16 * T + 4 * quad + r, gj = 16 * kh + l15;
      Gm[gi * 68 + gj]      = cg[r] + (gi == gj ? 1e-6f : 0.f);
      Gm[gi * 68 + 32 + gj] = (gi == gj) ? 1.f : 0.f;
    }
  }
  __syncthreads();

  // Gauss-Jordan on wave 0: lane = augmented column
  if (wv == 0) {
    float gcol[32];
    #pragma unroll
    for (int i = 0; i < 32; ++i) gcol[i] = Gm[i * 68 + lane];
    #pragma unroll
    for (int k = 0; k < 32; ++k) {
      float ckk  = __shfl(gcol[k], k);
      float ipiv = 1.f / ckk;
      float pivj = gcol[k] * ipiv;
      gcol[k] = pivj;
      #pragma unroll
      for (int i = 0; i < 32; ++i) {
        if (i == k) continue;
        float cki = __shfl(gcol[i], k);
        gcol[i] = fmaf(-cki, pivj, gcol[i]);
      }
    }
    if (lane >= 32) {
      #pragma unroll
      for (int i = 0; i < 32; ++i) GinvL[i * 32 + (lane - 32)] = gcol[i];
    }
  }
  __syncthreads();

  // KAT[n=t][m] = sum_p As[p][n] * Ginv[p][m]
  {
    float res[32];
    #pragma unroll
    for (int m = 0; m < 32; ++m) res[m] = 0.f;
    for (int p = 0; p < 32; ++p) {
      float av = As[p * 256 + t];
      #pragma unroll
      for (int m4 = 0; m4 < 8; ++m4) {
        f4v g = *(const f4v*)&GinvL[p * 32 + 4 * m4];
        res[4 * m4 + 0] = fmaf(av, g[0], res[4 * m4 + 0]);
        res[4 * m4 + 1] = fmaf(av, g[1], res[4 * m4 + 1]);
        res[4 * m4 + 2] = fmaf(av, g[2], res[4 * m4 + 2]);
        res[4 * m4 + 3] = fmaf(av, g[3], res[4 * m4 + 3]);
      }
    }
    #pragma unroll
    for (int m4 = 0; m4 < 8; ++m4) {
      f4v v = {res[4 * m4], res[4 * m4 + 1], res[4 * m4 + 2], res[4 * m4 + 3]};
      *(f4v*)&KAT[t * 32 + 4 * m4] = v;
    }
  }
}

// ---------------------------------------------------------------------------
// k_main: 512 threads (8 waves), TR=16 rows/block, grid 256 = 1 block/CU.
// UN-FUSED iteration (two small GEMMs), phase A k-split across ALL 8 waves:
//   R1-R6 lesson: this compiler hard-caps VGPR at 256/(W/4)/2 per lane
//   (512-thr -> 128, always). Fused Q needs 128 VGPR of operand alone ->
//   remat (L2-bound 205us) or spill (630us). The un-fused operands (A, KAT
//   fragments) cost only 32 VGPR/lane -> fits the 128 cap with room.
//   Phase A: wave (T=wv&1, kq=wv>>1): partial r^T over k-quarter kq
//     (6 MFMA) -> fp32 partial into pbuf. ONE barrier.
//   Phase B: each wave gathers the 4 partials directly in MFMA B-fragment
//     layout (8 ds_read_b128 + adds; C-layout algebra: value (m,row) of
//     tile T',kq sits at f4v slot [(T'*4+kq)*64 + row + 16*(m&15>>2)],
//     reg m&3), splits to bf16, w^T = KAT r^T (6 MFMA), z-update in regs,
//     publish z to the other zfrag buffer. ONE barrier.
//   2 barriers/iter, all waves busy in both phases, no serial 2-wave GEMM.
// ---------------------------------------------------------------------------
__global__ __launch_bounds__(512)
void k_main(
    const float* __restrict__ x,  const float* __restrict__ bmat,
    const float* __restrict__ W1, const float* __restrict__ b1,
    const float* __restrict__ W2, const float* __restrict__ b2,
    const float* __restrict__ W3, const float* __restrict__ b3,
    const float* __restrict__ A,  const float* __restrict__ KAT,
    const int* __restrict__ n_iter_p, float* __restrict__ out) {

  __shared__ __align__(16) float    ubuf[8768];    // MLP scratch; ys; then pbuf
  // zfrag double buffer at 0 / 4096; padded so LDS ~84 KB -> 1 block/CU.
  __shared__ __align__(16) unsigned zfrag[12288];

  const int t = threadIdx.x;
  const int lane = t & 63, wv = t >> 6, quad = lane >> 4, l15 = lane & 15;
  const int row0 = blockIdx.x * TR;

  float* xs = ubuf;            // [16][132]
  float* h1 = ubuf + 2112;     // [16][208]
  float* h2 = ubuf + 5440;     // [16][208]
  float* ys = ubuf;            // [16][260] (xs+h1 dead by then)

  {
    int r = t >> 5, c4 = t & 31;
    *(f4v*)&xs[r * 132 + 4 * c4] = *(const f4v*)&x[(size_t)(row0 + r) * 128 + 4 * c4];
  }
  __syncthreads();

  // ---- MLP: 2 rows per wave (proven 512-thread version) ----
  {
    const int rg = wv, oc = lane;
    const bool g3 = (oc < 8);    // HID=200: col oc+192 valid iff oc<8
    float acc[4][2];

    // L1: 128 -> 200, relu
    #pragma unroll
    for (int oi = 0; oi < 4; ++oi) { acc[oi][0] = 0.f; acc[oi][1] = 0.f; }
    for (int k4 = 0; k4 < 32; ++k4) {
      f4v xv0 = *(const f4v*)&xs[(2 * rg + 0) * 132 + 4 * k4];
      f4v xv1 = *(const f4v*)&xs[(2 * rg + 1) * 132 + 4 * k4];
      #pragma unroll
      for (int kk = 0; kk < 4; ++kk) {
        const float* wr = W1 + (4 * k4 + kk) * 200 + oc;
        float w0 = wr[0], w1c = wr[64], w2c = wr[128];
        float w3c = g3 ? wr[192] : 0.f;
        acc[0][0] = fmaf(xv0[kk], w0, acc[0][0]);  acc[0][1] = fmaf(xv1[kk], w0, acc[0][1]);
        acc[1][0] = fmaf(xv0[kk], w1c, acc[1][0]); acc[1][1] = fmaf(xv1[kk], w1c, acc[1][1]);
        acc[2][0] = fmaf(xv0[kk], w2c, acc[2][0]); acc[2][1] = fmaf(xv1[kk], w2c, acc[2][1]);
        acc[3][0] = fmaf(xv0[kk], w3c, acc[3][0]); acc[3][1] = fmaf(xv1[kk], w3c, acc[3][1]);
      }
    }
    #pragma unroll
    for (int oi = 0; oi < 4; ++oi) {
      if (oi == 3 && !g3) continue;
      float bb = b1[oc + 64 * oi];
      h1[(2 * rg + 0) * 208 + oc + 64 * oi] = fmaxf(acc[oi][0] + bb, 0.f);
      h1[(2 * rg + 1) * 208 + oc + 64 * oi] = fmaxf(acc[oi][1] + bb, 0.f);
    }
    __syncthreads();

    // L2: 200 -> 200, relu
    #pragma unroll
    for (int oi = 0; oi < 4; ++oi) { acc[oi][0] = 0.f; acc[oi][1] = 0.f; }
    for (int k4 = 0; k4 < 50; ++k4) {
      f4v xv0 = *(const f4v*)&h1[(2 * rg + 0) * 208 + 4 * k4];
      f4v xv1 = *(const f4v*)&h1[(2 * rg + 1) * 208 + 4 * k4];
      #pragma unroll
      for (int kk = 0; kk < 4; ++kk) {
        const float* wr = W2 + (4 * k4 + kk) * 200 + oc;
        float w0 = wr[0], w1c = wr[64], w2c = wr[128];
        float w3c = g3 ? wr[192] : 0.f;
        acc[0][0] = fmaf(xv0[kk], w0, acc[0][0]);  acc[0][1] = fmaf(xv1[kk], w0, acc[0][1]);
        acc[1][0] = fmaf(xv0[kk], w1c, acc[1][0]); acc[1][1] = fmaf(xv1[kk], w1c, acc[1][1]);
        acc[2][0] = fmaf(xv0[kk], w2c, acc[2][0]); acc[2][1] = fmaf(xv1[kk], w2c, acc[2][1]);
        acc[3][0] = fmaf(xv0[kk], w3c, acc[3][0]); acc[3][1] = fmaf(xv1[kk], w3c, acc[3][1]);
      }
    }
    #pragma unroll
    for (int oi = 0; oi < 4; ++oi) {
      if (oi == 3 && !g3) continue;
      float bb = b2[oc + 64 * oi];
      h2[(2 * rg + 0) * 208 + oc + 64 * oi] = fmaxf(acc[oi][0] + bb, 0.f);
      h2[(2 * rg + 1) * 208 + oc + 64 * oi] = fmaxf(acc[oi][1] + bb, 0.f);
    }
    __syncthreads();

    // L3: 200 -> 256 (no relu) -> ys
    #pragma unroll
    for (int oi = 0; oi < 4; ++oi) { acc[oi][0] = 0.f; acc[oi][1] = 0.f; }
    for (int k4 = 0; k4 < 50; ++k4) {
      f4v xv0 = *(const f4v*)&h2[(2 * rg + 0) * 208 + 4 * k4];
      f4v xv1 = *(const f4v*)&h2[(2 * rg + 1) * 208 + 4 * k4];
      #pragma unroll
      for (int kk = 0; kk < 4; ++kk) {
        const float* wr = W3 + (4 * k4 + kk) * 256 + oc;
        float w0 = wr[0], w1c = wr[64], w2c = wr[128], w3c = wr[192];
        acc[0][0] = fmaf(xv0[kk], w0, acc[0][0]);  acc[0][1] = fmaf(xv1[kk], w0, acc[0][1]);
        acc[1][0] = fmaf(xv0[kk], w1c, acc[1][0]); acc[1][1] = fmaf(xv1[kk], w1c, acc[1][1]);
        acc[2][0] = fmaf(xv0[kk], w2c, acc[2][0]); acc[2][1] = fmaf(xv1[kk], w2c, acc[2][1]);
        acc[3][0] = fmaf(xv0[kk], w3c, acc[3][0]); acc[3][1] = fmaf(xv1[kk], w3c, acc[3][1]);
      }
    }
    __syncthreads();   // reads of h2/xs done before ys overlays ubuf
    #pragma unroll
    for (int oi = 0; oi < 4; ++oi) {
      float bb = b3[oc + 64 * oi];
      ys[(2 * rg + 0) * 260 + oc + 64 * oi] = acc[oi][0] + bb;
      ys[(2 * rg + 1) * 260 + oc + 64 * oi] = acc[oi][1] + bb;
    }
  }
  __syncthreads();

  // ---- iteration-invariant operand fragments (small: ~32 VGPR total) ----
  // Phase A role: T = m-tile, kq = k-quarter (ksteps 2kq, 2kq+1).
  const int T = wv & 1, kq = wv >> 1;
  short8 aah[2], aal[2];
  #pragma unroll
  for (int ss = 0; ss < 2; ++ss) {
    const int s = 2 * kq + ss;
    const float* ap = A + (size_t)(l15 + 16 * T) * 256 + 32 * s + 8 * quad;
    float v[8];
    #pragma unroll
    for (int j = 0; j < 8; ++j) v[j] = ap[j];
    split8(v, aah[ss], aal[ss]);
  }
  f4v binit = {0.f, 0.f, 0.f, 0.f};
  if (kq == 0) {
    f4v bv = *(const f4v*)&bmat[(size_t)(row0 + l15) * 32 + 16 * T + 4 * quad];
    binit = -bv;
  }

  short8 kanh[2], kanl[2];       // phase-B A-op: KAT n-tiles U = 2wv, 2wv+1
  #pragma unroll
  for (int u = 0; u < 2; ++u) {
    const int U = 2 * wv + u;
    const float* kp = KAT + (size_t)(16 * U + l15) * 32 + 8 * quad;
    float v[8];
    #pragma unroll
    for (int j = 0; j < 8; ++j) v[j] = kp[j];
    split8(v, kanh[u], kanl[u]);
  }
  #pragma unroll
  for (int ss = 0; ss < 2; ++ss)
    asm volatile("" : "+v"(aah[ss]), "+v"(aal[ss]), "+v"(kanh[ss]), "+v"(kanl[ss]));

  // ---- zfrag write offsets + z init from y; publish buffer 0 ----
  int zoff[2];
  float zr[2][4];
  #pragma unroll
  for (int u = 0; u < 2; ++u) {
    const int U = 2 * wv + u;
    const int qp = 2 * (U & 1) + (quad >> 1);
    zoff[u] = ((U >> 1) * 2) * 256 + qp * 64 + l15 * 4 + 2 * (quad & 1);
    f4v yv = *(const f4v*)&ys[l15 * 260 + 16 * U + 4 * quad];
    #pragma unroll
    for (int r = 0; r < 4; ++r) zr[u][r] = yv[r];
    pack_write(&zfrag[zoff[u]], zr[u][0], zr[u][1], zr[u][2], zr[u][3]);
  }
  __syncthreads();

  const int niter = n_iter_p[0];
  const int zrd = lane * 4;
  float* pbuf = ubuf;                         // 8 KB partial buffer (ubuf dead)
  const int pwr = ((T * 4 + kq) * 64 + lane) * 4;   // phase-A partial slot
  const int Tq = quad >> 1, qs = quad & 1;          // phase-B gather role
  const int prdA = (Tq * 4 * 64 + l15 + 32 * qs) * 4;  // kq=0 base (j=0..3)

  for (int it = 0; it <= niter; ++it) {
    const unsigned* zb = zfrag + ((it & 1) << 12);         // read buffer
    unsigned*       zw = zfrag + (((it & 1) ^ 1) << 12);   // write buffer

    // ===== Phase A: partial r^T over k-quarter kq (6 MFMA, 2 chains) =====
    {
      const int s0 = 2 * kq;
      short8 zh0 = *(const short8*)&zb[(2 * s0 + 0) * 256 + zrd];
      short8 zl0 = *(const short8*)&zb[(2 * s0 + 1) * 256 + zrd];
      short8 zh1 = *(const short8*)&zb[(2 * s0 + 2) * 256 + zrd];
      short8 zl1 = *(const short8*)&zb[(2 * s0 + 3) * 256 + zrd];
      f4v c0 = binit;
      f4v c1 = {0.f, 0.f, 0.f, 0.f};
      c0 = mfma16(aah[0], zh0, c0);  c1 = mfma16(aah[1], zh1, c1);
      c0 = mfma16(aal[0], zh0, c0);  c1 = mfma16(aal[1], zh1, c1);
      c0 = mfma16(aah[0], zl0, c0);  c1 = mfma16(aah[1], zl1, c1);
      *(f4v*)&pbuf[pwr] = c0 + c1;
    }
    __syncthreads();

    // ===== Phase B: gather r in B-frag layout, w^T = KA^T r^T =====
    f4v va = {0.f, 0.f, 0.f, 0.f}, vb = {0.f, 0.f, 0.f, 0.f};
    #pragma unroll
    for (int k = 0; k < 4; ++k) {
      const int base = prdA + k * 256;        // (Tq*4+k)*64 slots of f4v
      va += *(const f4v*)&pbuf[base];
      vb += *(const f4v*)&pbuf[base + 64];    // +16 lanes
    }
    float rv[8] = {va[0], va[1], va[2], va[3], vb[0], vb[1], vb[2], vb[3]};
    short8 rh, rl;
    split8(rv, rh, rl);

    f4v cB[2];
    #pragma unroll
    for (int u = 0; u < 2; ++u) {
      f4v cc = {0.f, 0.f, 0.f, 0.f};
      cc = mfma16(kanh[u], rh, cc);
      cc = mfma16(kanl[u], rh, cc);
      cc = mfma16(kanh[u], rl, cc);
      cB[u] = cc;
    }

    if (it < niter) {
      #pragma unroll
      for (int u = 0; u < 2; ++u) {
        float zn[4];
        #pragma unroll
        for (int r = 0; r < 4; ++r) {
          float z = zr[u][r], wvv = cB[u][r];
          float vv = fminf(fmaxf(z - 2.f * wvv, 0.f), 1.f);  // clip(2u - z)
          zn[r] = fmaf(1.7f, vv - z + wvv, z);               // z += 1.7*(v-u)
          zr[u][r] = zn[r];
        }
        pack_write(&zw[zoff[u]], zn[0], zn[1], zn[2], zn[3]);
      }
      __syncthreads();
    } else {
      #pragma unroll
      for (int u = 0; u < 2; ++u) {
        const int U = 2 * wv + u;
        f4v ov;
        #pragma unroll
        for (int r = 0; r < 4; ++r) ov[r] = zr[u][r] - cB[u][r];
        *(f4v*)&out[(size_t)(row0 + l15) * 256 + 16 * U + 4 * quad] = ov;
      }
    }
  }
}

// ---------------------------------------------------------------------------
extern "C" void kernel_launch(void* const* d_in, const int* in_sizes, int n_in,
                              void* d_out, int out_size, void* d_ws, size_t ws_size,
                              hipStream_t stream) {
  const float* x    = (const float*)d_in[0];
  const float* bmat = (const float*)d_in[1];
  const float* W1   = (const float*)d_in[2];
  const float* b1   = (const float*)d_in[3];
  const float* W2   = (const float*)d_in[4];
  const float* b2   = (const float*)d_in[5];
  const float* W3   = (const float*)d_in[6];
  const float* b3   = (const float*)d_in[7];
  const float* A    = (const float*)d_in[8];
  const int*  n_it  = (const int*)d_in[10];

  float* KAT = (float*)d_ws;          // 256*32 floats = 32 KB
  float* out = (float*)d_out;

  hipLaunchKernelGGL(k_prep, dim3(1), dim3(256), 0, stream, A, KAT);
  hipLaunchKernelGGL(k_main, dim3(Bn / TR), dim3(512), 0, stream,
                     x, bmat, W1, b1, W2, b2, W3, b3, A, KAT, n_it, out);
}